// Round 2
// baseline (774.938 us; speedup 1.0000x reference)
//
#include <hip/hip_runtime.h>
#include <hip/hip_bf16.h>
#include <float.h>

#define N_PTS 6144
#define D_IN  512
#define H1_DIM 256
#define H2_DIM 128
#define G_DIM  64
#define KNN    32
#define NOUT   22

// C[64x64 tile] = A[M,K] * B[K,N] (optionally B given transposed as [N,K]),
// fp32 accumulate, optional bias + relu. Block = 256 threads, 4x4/thread.
template<bool TRANSB, bool RELU, bool BIAS>
__global__ __launch_bounds__(256) void gemm64(const float* __restrict__ A,
    const float* __restrict__ B, const float* __restrict__ bias,
    float* __restrict__ C, int K, int ldA, int ldB, int ldC)
{
  __shared__ float As[16][65];
  __shared__ float Bs[16][65];
  const int tid = threadIdx.x;
  const int m0 = blockIdx.y * 64, n0 = blockIdx.x * 64;
  float acc[4][4] = {};
  const int tx = tid & 15, ty = tid >> 4;
  const int ka = tid & 15, ma = tid >> 4;   // strided staging coords
  const int nb = tid & 63, kb = tid >> 6;

  for (int k0 = 0; k0 < K; k0 += 16) {
    #pragma unroll
    for (int p = 0; p < 4; ++p) {
      int m = ma + p * 16;
      As[ka][m] = A[(size_t)(m0 + m) * ldA + k0 + ka];
    }
    if (!TRANSB) {
      #pragma unroll
      for (int p = 0; p < 4; ++p) {
        int k = kb + p * 4;
        Bs[k][nb] = B[(size_t)(k0 + k) * ldB + n0 + nb];
      }
    } else {
      #pragma unroll
      for (int p = 0; p < 4; ++p) {
        int n = ma + p * 16;
        Bs[ka][n] = B[(size_t)(n0 + n) * ldB + k0 + ka];
      }
    }
    __syncthreads();
    #pragma unroll
    for (int k = 0; k < 16; ++k) {
      float a[4], b[4];
      #pragma unroll
      for (int r = 0; r < 4; ++r) a[r] = As[k][ty * 4 + r];
      #pragma unroll
      for (int c = 0; c < 4; ++c) b[c] = Bs[k][tx * 4 + c];
      #pragma unroll
      for (int r = 0; r < 4; ++r)
        #pragma unroll
        for (int c = 0; c < 4; ++c)
          acc[r][c] = fmaf(a[r], b[c], acc[r][c]);
    }
    __syncthreads();
  }
  #pragma unroll
  for (int r = 0; r < 4; ++r) {
    int m = m0 + ty * 4 + r;
    #pragma unroll
    for (int c = 0; c < 4; ++c) {
      int n = n0 + tx * 4 + c;
      float v = acc[r][c];
      if (BIAS) v += bias[n];
      if (RELU) v = fmaxf(v, 0.0f);
      C[(size_t)m * ldC + n] = v;
    }
  }
}

// Collapse tiled heads: Wc[64][22] = sum of the 8 row-blocks of cls_W / dsc_W,
// bc[22] = concat(cls_b, dsc_b.flatten())
__global__ void prep_head(const float* __restrict__ cW, const float* __restrict__ cb,
                          const float* __restrict__ dW, const float* __restrict__ db,
                          float* __restrict__ Wc, float* __restrict__ bc)
{
  int t = threadIdx.x;
  for (int idx = t; idx < 64 * NOUT; idx += 256) {
    int g = idx / NOUT, c = idx % NOUT;
    float s = 0.f;
    if (c < 16) {
      for (int r = 0; r < 8; ++r) s += cW[(r * 64 + g) * 16 + c];
    } else {
      int k = (c - 16) >> 1, o = (c - 16) & 1;
      for (int r = 0; r < 8; ++r) s += dW[k * 1024 + (r * 64 + g) * 2 + o];
    }
    Wc[idx] = s;
  }
  if (t < NOUT) bc[t] = (t < 16) ? cb[t] : db[t - 16];
}

// per-row: sq = ||h||^2, f1 = Wh . a[:64], f2 = Wh . a[64:]
__global__ void row_stats(const float* __restrict__ h, const float* __restrict__ Wh,
                          const float* __restrict__ ga, float* __restrict__ sq,
                          float* __restrict__ f1, float* __restrict__ f2)
{
  int i = blockIdx.x * 256 + threadIdx.x;
  const float* hr = h + (size_t)i * H2_DIM;
  float s = 0.f;
  for (int k = 0; k < H2_DIM; ++k) { float v = hr[k]; s = fmaf(v, v, s); }
  sq[i] = s;
  const float* wr = Wh + (size_t)i * G_DIM;
  float a = 0.f, b = 0.f;
  for (int g = 0; g < G_DIM; ++g) {
    float w = wr[g];
    a = fmaf(w, ga[g], a);
    b = fmaf(w, ga[G_DIM + g], b);
  }
  f1[i] = a; f2[i] = b;
}

// One block per row: top-32 smallest of (sq_j - 2*S_ij), j != i, then fused
// 33-entry masked softmax (leaky_relu scores) + sparse att@Wh + elu + 64->22 head.
__global__ __launch_bounds__(256) void topk_att(const float* __restrict__ Sb,
    const float* __restrict__ sq, const float* __restrict__ f1, const float* __restrict__ f2,
    const float* __restrict__ Wh, const float* __restrict__ Wc, const float* __restrict__ bc,
    float* __restrict__ out, int m0)
{
  const int t = threadIdx.x;
  const int i = m0 + blockIdx.x;
  const float* Srow = Sb + (size_t)blockIdx.x * N_PTS;

  __shared__ float redv[4];
  __shared__ int   redj[4];
  __shared__ int   neigh[33];
  __shared__ float attL[33];
  __shared__ float hp4[4][64];
  __shared__ float hpf[64];
  __shared__ float WcL[64 * NOUT];

  for (int idx = t; idx < 64 * NOUT; idx += 256) WcL[idx] = Wc[idx];

  // keys live in registers: j = t + 256*m, m in [0,24)
  float key[24];
  #pragma unroll
  for (int m = 0; m < 24; ++m) {
    int j = t + (m << 8);
    float kk = fmaf(-2.f, Srow[j], sq[j]);
    key[m] = (j == i) ? FLT_MAX : kk;
  }
  float lv = key[0]; int lm = 0;
  #pragma unroll
  for (int m = 1; m < 24; ++m) if (key[m] < lv) { lv = key[m]; lm = m; }
  int lj = t + (lm << 8);

  for (int it = 0; it < KNN; ++it) {
    float v = lv; int j = lj;
    #pragma unroll
    for (int off = 32; off > 0; off >>= 1) {
      float ov = __shfl_xor(v, off);
      int   oj = __shfl_xor(j, off);
      if (ov < v || (ov == v && oj < j)) { v = ov; j = oj; }
    }
    if ((t & 63) == 0) { redv[t >> 6] = v; redj[t >> 6] = j; }
    __syncthreads();
    v = redv[0]; j = redj[0];
    #pragma unroll
    for (int w = 1; w < 4; ++w) {
      float ov = redv[w]; int oj = redj[w];
      if (ov < v || (ov == v && oj < j)) { v = ov; j = oj; }
    }
    if (t == 0) neigh[it] = j;
    if ((j & 255) == t) {            // owner removes and re-derives its local min
      int slot = j >> 8;
      #pragma unroll
      for (int m = 0; m < 24; ++m) if (m == slot) key[m] = FLT_MAX;  // static idx, stays in regs
      lv = key[0]; lm = 0;
      #pragma unroll
      for (int m = 1; m < 24; ++m) if (key[m] < lv) { lv = key[m]; lm = m; }
      lj = t + (lm << 8);
    }
    __syncthreads();
  }
  if (t == 0) neigh[32] = i;   // self loop
  __syncthreads();

  // masked softmax over the 33 live entries (first wave only)
  if (t < 64) {
    float e = -FLT_MAX;
    if (t < 33) {
      float raw = f1[i] + f2[neigh[t]];
      e = raw > 0.f ? raw : 0.2f * raw;     // leaky_relu 0.2
    }
    float mx = e;
    #pragma unroll
    for (int off = 32; off > 0; off >>= 1) mx = fmaxf(mx, __shfl_xor(mx, off));
    float ex = (t < 33) ? expf(e - mx) : 0.f;
    float sm = ex;
    #pragma unroll
    for (int off = 32; off > 0; off >>= 1) sm += __shfl_xor(sm, off);
    if (t < 33) attL[t] = ex / sm;
  }
  __syncthreads();

  // hp[g] = sum_m att[m] * Wh[neigh[m]][g]
  {
    int g = t & 63, q = t >> 6;
    float s = 0.f;
    for (int m = q; m < 33; m += 4)
      s = fmaf(attL[m], Wh[(size_t)neigh[m] * G_DIM + g], s);
    hp4[q][g] = s;
  }
  __syncthreads();
  if (t < 64) {
    float v = hp4[0][t] + hp4[1][t] + hp4[2][t] + hp4[3][t];
    hpf[t] = v > 0.f ? v : expm1f(v);       // elu
  }
  __syncthreads();
  if (t < NOUT) {
    float o = bc[t];
    for (int g = 0; g < 64; ++g) o = fmaf(hpf[g], WcL[g * NOUT + t], o);
    out[(size_t)i * NOUT + t] = o;
  }
}

extern "C" void kernel_launch(void* const* d_in, const int* in_sizes, int n_in,
                              void* d_out, int out_size, void* d_ws, size_t ws_size,
                              hipStream_t stream)
{
  const float* x  = (const float*)d_in[0];
  const float* W0 = (const float*)d_in[1];
  const float* b0 = (const float*)d_in[2];
  const float* W1 = (const float*)d_in[3];
  const float* b1 = (const float*)d_in[4];
  const float* gW = (const float*)d_in[5];
  const float* ga = (const float*)d_in[6];
  const float* cW = (const float*)d_in[7];
  const float* cb = (const float*)d_in[8];
  const float* dW = (const float*)d_in[9];
  const float* db = (const float*)d_in[10];
  float* out = (float*)d_out;

  float* ws = (float*)d_ws;
  float* h1 = ws;                                  // 6144*256
  float* h  = h1 + (size_t)N_PTS * H1_DIM;         // 6144*128
  float* Wh = h  + (size_t)N_PTS * H2_DIM;         // 6144*64
  float* sq = Wh + (size_t)N_PTS * G_DIM;          // 6144
  float* f1 = sq + N_PTS;                          // 6144
  float* f2 = f1 + N_PTS;                          // 6144
  float* Wc = f2 + N_PTS;                          // 64*22
  float* bc = Wc + 64 * NOUT;                      // 22 (padded to 64)
  float* Sb = bc + 64;                             // rowblk*6144 panel

  // Pick the largest panel height (divisor of 6144, multiple of 64) that fits ws.
  size_t base = (size_t)(Sb - ws);
  long long avail = (long long)(ws_size / 4) - (long long)base;
  int rowblk = 64;
  const int cand[] = {768, 512, 384, 256, 192, 128, 64};
  for (int c : cand) {
    if ((long long)c * N_PTS <= avail) { rowblk = c; break; }
  }

  prep_head<<<1, 256, 0, stream>>>(cW, cb, dW, db, Wc, bc);

  // h1 = relu(x @ W0 + b0)
  gemm64<false, true, true><<<dim3(H1_DIM / 64, N_PTS / 64), 256, 0, stream>>>(
      x, W0, b0, h1, D_IN, D_IN, H1_DIM, H1_DIM);
  // h = relu(h1 @ W1 + b1)
  gemm64<false, true, true><<<dim3(H2_DIM / 64, N_PTS / 64), 256, 0, stream>>>(
      h1, W1, b1, h, H1_DIM, H1_DIM, H2_DIM, H2_DIM);
  // Wh = h @ gat_W
  gemm64<false, false, false><<<dim3(G_DIM / 64, N_PTS / 64), 256, 0, stream>>>(
      h, gW, nullptr, Wh, H2_DIM, H2_DIM, G_DIM, G_DIM);

  row_stats<<<N_PTS / 256, 256, 0, stream>>>(h, Wh, ga, sq, f1, f2);

  // Row-blocked Gram panel + fused topk/attention/head
  for (int b = 0; b < N_PTS / rowblk; ++b) {
    gemm64<true, false, false><<<dim3(N_PTS / 64, rowblk / 64), 256, 0, stream>>>(
        h + (size_t)b * rowblk * H2_DIM, h, nullptr, Sb, H2_DIM, H2_DIM, H2_DIM, N_PTS);
    topk_att<<<rowblk, 256, 0, stream>>>(Sb, sq, f1, f2, Wh, Wc, bc, out, b * rowblk);
  }
}

// Round 4
// 425.781 us; speedup vs baseline: 1.8200x; 1.8200x over previous
//
#include <hip/hip_runtime.h>
#include <float.h>

#define N_PTS 6144
#define D_IN  512
#define H1_DIM 256
#define H2_DIM 128
#define G_DIM  64
#define KNN    32
#define NOUT   22

typedef short s8v __attribute__((ext_vector_type(8)));   // 8 bf16 in 4 VGPR
typedef float f32x4 __attribute__((ext_vector_type(4)));
typedef unsigned short u16;

__device__ __forceinline__ u16 f2bf(float f) {
  unsigned u = __float_as_uint(f);
  u += 0x7FFFu + ((u >> 16) & 1u);          // RNE to bf16
  return (u16)(u >> 16);
}
__device__ __forceinline__ float bf2f(u16 s) {
  return __uint_as_float(((unsigned)s) << 16);
}
__device__ __forceinline__ void split3(float v, u16& a0, u16& a1, u16& a2) {
  a0 = f2bf(v);
  float r1 = v - bf2f(a0);
  a1 = f2bf(r1);
  a2 = f2bf(r1 - bf2f(a1));
}

// ---------------------------------------------------------------------------
// MFMA GEMM: C[M,N] = A[M,K] * B^T[N,K], 3-way bf16 split (24-bit mantissa),
// 6-term product schedule -> fp32-equivalent accuracy.
// Tile 128x64, BK=64, 4 waves (2x2), wave tile 64x32 (MT=4, NT=2).
// LDS XOR slot-swizzle: byte-slot' = slot ^ (row&7).
// ---------------------------------------------------------------------------
template<bool AF32, bool BIAS, bool RELU, bool WF32, bool WSPLIT>
__global__ __launch_bounds__(256) void mfma_gemm(
    const void* __restrict__ A0any, const u16* __restrict__ A1_, const u16* __restrict__ A2_,
    const u16* __restrict__ B0_, const u16* __restrict__ B1_, const u16* __restrict__ B2_,
    const float* __restrict__ bias,
    float* __restrict__ Cf, u16* __restrict__ C0, u16* __restrict__ C1, u16* __restrict__ C2,
    int K, int ldC)
{
  const int MT = 4, NT = 2;
  const int BM = 128, BN = 64;
  __shared__ u16 lds[(BM + BN) * 64 * 3];                 // 72 KB
  u16* Ap[3] = { lds, lds + BM * 64, lds + 2 * BM * 64 };
  u16* Bp[3] = { lds + 3 * BM * 64, lds + 3 * BM * 64 + BN * 64, lds + 3 * BM * 64 + 2 * BN * 64 };

  const int t = threadIdx.x;
  const int lane = t & 63, wave = t >> 6;
  const int wm = wave >> 1, wn = wave & 1;
  const int m0 = blockIdx.y * BM, n0 = blockIdx.x * BN;

  f32x4 acc[MT][NT] = {};

  for (int k0 = 0; k0 < K; k0 += 64) {
    if (k0) __syncthreads();
    // ---- stage A tile (128 rows x 64 cols x 3 planes) ----
    if (AF32) {
      const float* A = (const float*)A0any;
      for (int c = t; c < BM * 8; c += 256) {
        int row = c >> 3, slot = c & 7;
        const float* g = A + (size_t)(m0 + row) * K + k0 + slot * 8;
        int dst = row * 64 + ((slot ^ (row & 7)) << 3);
        s8v v0, v1, v2;
        #pragma unroll
        for (int e = 0; e < 8; ++e) {
          u16 a0, a1, a2;
          split3(g[e], a0, a1, a2);
          v0[e] = (short)a0; v1[e] = (short)a1; v2[e] = (short)a2;
        }
        *(s8v*)(Ap[0] + dst) = v0;
        *(s8v*)(Ap[1] + dst) = v1;
        *(s8v*)(Ap[2] + dst) = v2;
      }
    } else {
      const u16* As[3] = { (const u16*)A0any, A1_, A2_ };
      for (int c = t; c < BM * 8; c += 256) {
        int row = c >> 3, slot = c & 7;
        size_t g = (size_t)(m0 + row) * K + k0 + slot * 8;
        int dst = row * 64 + ((slot ^ (row & 7)) << 3);
        #pragma unroll
        for (int p = 0; p < 3; ++p)
          *(s8v*)(Ap[p] + dst) = *(const s8v*)(As[p] + g);
      }
    }
    // ---- stage B tile (64 rows x 64 cols x 3 planes) ----
    {
      const u16* Bs[3] = { B0_, B1_, B2_ };
      for (int c = t; c < BN * 8; c += 256) {
        int row = c >> 3, slot = c & 7;
        size_t g = (size_t)(n0 + row) * K + k0 + slot * 8;
        int dst = row * 64 + ((slot ^ (row & 7)) << 3);
        #pragma unroll
        for (int p = 0; p < 3; ++p)
          *(s8v*)(Bp[p] + dst) = *(const s8v*)(Bs[p] + g);
      }
    }
    __syncthreads();

    #pragma unroll
    for (int ks = 0; ks < 2; ++ks) {
      s8v af[3][MT], bf[3][NT];
      #pragma unroll
      for (int mt = 0; mt < MT; ++mt) {
        int r = wm * 64 + mt * 16 + (lane & 15);
        int slot = (ks * 4 + (lane >> 4)) ^ (r & 7);
        int off = r * 64 + slot * 8;
        #pragma unroll
        for (int p = 0; p < 3; ++p) af[p][mt] = *(const s8v*)(Ap[p] + off);
      }
      #pragma unroll
      for (int nt = 0; nt < NT; ++nt) {
        int r = wn * 32 + nt * 16 + (lane & 15);
        int slot = (ks * 4 + (lane >> 4)) ^ (r & 7);
        int off = r * 64 + slot * 8;
        #pragma unroll
        for (int p = 0; p < 3; ++p) bf[p][nt] = *(const s8v*)(Bp[p] + off);
      }
      #pragma unroll
      for (int mt = 0; mt < MT; ++mt)
        #pragma unroll
        for (int nt = 0; nt < NT; ++nt) {
          f32x4 a = acc[mt][nt];
          a = __builtin_amdgcn_mfma_f32_16x16x32_bf16(af[0][mt], bf[0][nt], a, 0, 0, 0);
          a = __builtin_amdgcn_mfma_f32_16x16x32_bf16(af[0][mt], bf[1][nt], a, 0, 0, 0);
          a = __builtin_amdgcn_mfma_f32_16x16x32_bf16(af[1][mt], bf[0][nt], a, 0, 0, 0);
          a = __builtin_amdgcn_mfma_f32_16x16x32_bf16(af[1][mt], bf[1][nt], a, 0, 0, 0);
          a = __builtin_amdgcn_mfma_f32_16x16x32_bf16(af[0][mt], bf[2][nt], a, 0, 0, 0);
          a = __builtin_amdgcn_mfma_f32_16x16x32_bf16(af[2][mt], bf[0][nt], a, 0, 0, 0);
          acc[mt][nt] = a;
        }
    }
  }

  // ---- epilogue: C/D layout col=lane&15, row=(lane>>4)*4+v ----
  #pragma unroll
  for (int mt = 0; mt < MT; ++mt) {
    #pragma unroll
    for (int nt = 0; nt < NT; ++nt) {
      int col = n0 + wn * 32 + nt * 16 + (lane & 15);
      float bv = BIAS ? bias[col] : 0.f;
      #pragma unroll
      for (int v = 0; v < 4; ++v) {
        int row = m0 + wm * 64 + mt * 16 + (lane >> 4) * 4 + v;
        float val = acc[mt][nt][v] + bv;
        if (RELU) val = fmaxf(val, 0.f);
        size_t o = (size_t)row * ldC + col;
        if (WF32) Cf[o] = val;
        if (WSPLIT) {
          u16 a0, a1, a2;
          split3(val, a0, a1, a2);
          C0[o] = a0; C1[o] = a1; C2[o] = a2;
        }
      }
    }
  }
}

// W [K,N] fp32 -> W^T 3-plane bf16 split [N,K]
__global__ void trans_split(const float* __restrict__ W, u16* __restrict__ p0,
                            u16* __restrict__ p1, u16* __restrict__ p2, int K, int N)
{
  int id = blockIdx.x * 256 + threadIdx.x;
  if (id >= K * N) return;
  int k = id / N, n = id % N;
  u16 a0, a1, a2;
  split3(W[id], a0, a1, a2);
  size_t o = (size_t)n * K + k;
  p0[o] = a0; p1[o] = a1; p2[o] = a2;
}

// Collapse tiled heads: Wc[64][22], bc[22]
__global__ void prep_head(const float* __restrict__ cW, const float* __restrict__ cb,
                          const float* __restrict__ dW, const float* __restrict__ db,
                          float* __restrict__ Wc, float* __restrict__ bc)
{
  int t = threadIdx.x;
  for (int idx = t; idx < 64 * NOUT; idx += 256) {
    int g = idx / NOUT, c = idx % NOUT;
    float s = 0.f;
    if (c < 16) {
      for (int r = 0; r < 8; ++r) s += cW[(r * 64 + g) * 16 + c];
    } else {
      int k = (c - 16) >> 1, o = (c - 16) & 1;
      for (int r = 0; r < 8; ++r) s += dW[k * 1024 + (r * 64 + g) * 2 + o];
    }
    Wc[idx] = s;
  }
  if (t < NOUT) bc[t] = (t < 16) ? cb[t] : db[t - 16];
}

__global__ void row_stats(const float* __restrict__ h, const float* __restrict__ Wh,
                          const float* __restrict__ ga, float* __restrict__ sq,
                          float* __restrict__ f1, float* __restrict__ f2)
{
  int i = blockIdx.x * 256 + threadIdx.x;
  const float* hr = h + (size_t)i * H2_DIM;
  float s = 0.f;
  for (int k = 0; k < H2_DIM; ++k) { float v = hr[k]; s = fmaf(v, v, s); }
  sq[i] = s;
  const float* wr = Wh + (size_t)i * G_DIM;
  float a = 0.f, b = 0.f;
  for (int g = 0; g < G_DIM; ++g) {
    float w = wr[g];
    a = fmaf(w, ga[g], a);
    b = fmaf(w, ga[G_DIM + g], b);
  }
  f1[i] = a; f2[i] = b;
}

// ---------------------------------------------------------------------------
// Per-row: radix-select 32 smallest keys (sq_j - 2*S_ij, j!=i), then fused
// masked softmax + sparse att@Wh + elu + 64->22 head.
// ---------------------------------------------------------------------------
__global__ __launch_bounds__(256) void topk_att(const float* __restrict__ Sb,
    const float* __restrict__ sq, const float* __restrict__ f1, const float* __restrict__ f2,
    const float* __restrict__ Wh, const float* __restrict__ Wc, const float* __restrict__ bc,
    float* __restrict__ out, int m0)
{
  const int t = threadIdx.x;
  const int lane = t & 63, wv = t >> 6;
  const int i = m0 + blockIdx.x;
  const float* Srow = Sb + (size_t)blockIdx.x * N_PTS;

  __shared__ int hist[256];
  __shared__ int wtot[4];
  __shared__ int sD0, sB0, sD1, sB1;
  __shared__ int wcnt, ccnt, ovf;
  __shared__ unsigned cand[64];
  __shared__ unsigned long long redr[4];
  __shared__ int neigh[33];
  __shared__ float attL[33];
  __shared__ float hp4[4][64];
  __shared__ float hpf[64];
  __shared__ float WcL[64 * NOUT];

  for (int idx = t; idx < 64 * NOUT; idx += 256) WcL[idx] = Wc[idx];

  // sortable-uint keys, 24 per thread (j = t + m*256)
  unsigned u[24];
  #pragma unroll
  for (int m = 0; m < 24; ++m) {
    int j = t + (m << 8);
    float f = fmaf(-2.f, Srow[j], sq[j]);
    unsigned ub = __float_as_uint(f);
    unsigned uu = (ub & 0x80000000u) ? ~ub : (ub | 0x80000000u);
    u[m] = (j == i) ? 0xFFFFFFFFu : uu;
  }

  hist[t] = 0;
  if (t == 0) { wcnt = 0; ccnt = 0; ovf = 0; }
  __syncthreads();
  #pragma unroll
  for (int m = 0; m < 24; ++m) atomicAdd(&hist[u[m] >> 24], 1);
  __syncthreads();
  {  // scan pass 1: digit-0 bucket of the 32nd smallest
    int v = hist[t], x = v;
    #pragma unroll
    for (int d = 1; d < 64; d <<= 1) { int o = __shfl_up(x, (unsigned)d); if (lane >= d) x += o; }
    if (lane == 63) wtot[wv] = x;
    __syncthreads();
    int off = 0;
    for (int w = 0; w < wv; ++w) off += wtot[w];
    int incl = x + off, excl = incl - v;
    if (excl < 32 && 32 <= incl) { sD0 = t; sB0 = excl; }
  }
  __syncthreads();
  const int D0 = sD0;
  const int need2 = 32 - sB0;
  hist[t] = 0;
  __syncthreads();
  #pragma unroll
  for (int m = 0; m < 24; ++m)
    if ((int)(u[m] >> 24) == D0) atomicAdd(&hist[(u[m] >> 16) & 255], 1);
  __syncthreads();
  {  // scan pass 2: digit-1 bucket
    int v = hist[t], x = v;
    #pragma unroll
    for (int d = 1; d < 64; d <<= 1) { int o = __shfl_up(x, (unsigned)d); if (lane >= d) x += o; }
    if (lane == 63) wtot[wv] = x;
    __syncthreads();
    int off = 0;
    for (int w = 0; w < wv; ++w) off += wtot[w];
    int incl = x + off, excl = incl - v;
    if (excl < need2 && need2 <= incl) { sD1 = t; sB1 = excl; }
  }
  __syncthreads();
  const unsigned P16 = ((unsigned)D0 << 8) | (unsigned)sD1;
  const int rem2 = need2 - sB1;

  // collect winners (prefix16 < P16) and tie-bucket candidates (== P16)
  #pragma unroll
  for (int m = 0; m < 24; ++m) {
    unsigned p = u[m] >> 16;
    int j = t + (m << 8);
    if (p < P16) {
      int w = atomicAdd(&wcnt, 1);
      neigh[w] = j;
    } else if (p == P16) {
      int c = atomicAdd(&ccnt, 1);
      if (c < 64) cand[c] = ((u[m] & 0xFFFFu) << 13) | (unsigned)j;
      else ovf = 1;
    }
  }
  __syncthreads();

  if (!ovf) {
    if (t < 64) {  // wave-0 bitonic sort of <=64 candidate ranks
      unsigned v = (lane < ccnt) ? cand[lane] : 0xFFFFFFFFu;
      for (int k = 2; k <= 64; k <<= 1)
        for (int j2 = k >> 1; j2 >= 1; j2 >>= 1) {
          unsigned o = __shfl_xor(v, j2);
          bool keepMin = ((lane & j2) == 0) == ((lane & k) == 0);
          v = keepMin ? (v < o ? v : o) : (v > o ? v : o);
        }
      if (lane < rem2) neigh[wcnt + lane] = (int)(v & 0x1FFFu);
      if (lane == 0) neigh[32] = i;
    }
  } else {
    // fallback: exact 32x min-extraction on (u, j) ranks (pathological ties)
    unsigned long long lv = ~0ull; int lm = 0;
    #pragma unroll
    for (int m = 0; m < 24; ++m) {
      unsigned long long rk = ((unsigned long long)u[m] << 13) | (unsigned)(t + (m << 8));
      if (rk < lv) { lv = rk; lm = m; }
    }
    for (int it = 0; it < KNN; ++it) {
      unsigned long long v = lv;
      for (int off2 = 32; off2 > 0; off2 >>= 1) {
        unsigned long long o = __shfl_xor(v, off2);
        if (o < v) v = o;
      }
      if (lane == 0) redr[wv] = v;
      __syncthreads();
      v = redr[0];
      for (int w = 1; w < 4; ++w) v = (redr[w] < v) ? redr[w] : v;
      if (t == 0) neigh[it] = (int)(v & 0x1FFFu);
      if (v == lv) {
        #pragma unroll
        for (int m = 0; m < 24; ++m) if (m == lm) u[m] = 0xFFFFFFFFu;
        lv = ~0ull; lm = 0;
        #pragma unroll
        for (int m = 0; m < 24; ++m) {
          unsigned long long rk = ((unsigned long long)u[m] << 13) | (unsigned)(t + (m << 8));
          if (rk < lv) { lv = rk; lm = m; }
        }
      }
      __syncthreads();
    }
    if (t == 0) neigh[32] = i;
  }
  __syncthreads();

  // masked softmax over 33 entries
  if (t < 64) {
    float e = -FLT_MAX;
    if (t < 33) {
      float raw = f1[i] + f2[neigh[t]];
      e = raw > 0.f ? raw : 0.2f * raw;
    }
    float mx = e;
    #pragma unroll
    for (int off = 32; off > 0; off >>= 1) mx = fmaxf(mx, __shfl_xor(mx, off));
    float ex = (t < 33) ? expf(e - mx) : 0.f;
    float sm = ex;
    #pragma unroll
    for (int off = 32; off > 0; off >>= 1) sm += __shfl_xor(sm, off);
    if (t < 33) attL[t] = ex / sm;
  }
  __syncthreads();

  {  // hp[g] = sum att[m] * Wh[neigh[m]][g]
    int g = t & 63, q = t >> 6;
    float s = 0.f;
    for (int m = q; m < 33; m += 4)
      s = fmaf(attL[m], Wh[(size_t)neigh[m] * G_DIM + g], s);
    hp4[q][g] = s;
  }
  __syncthreads();
  if (t < 64) {
    float v = hp4[0][t] + hp4[1][t] + hp4[2][t] + hp4[3][t];
    hpf[t] = v > 0.f ? v : expm1f(v);
  }
  __syncthreads();
  if (t < NOUT) {
    float o = bc[t];
    for (int g = 0; g < 64; ++g) o = fmaf(hpf[g], WcL[g * NOUT + t], o);
    out[(size_t)i * NOUT + t] = o;
  }
}

extern "C" void kernel_launch(void* const* d_in, const int* in_sizes, int n_in,
                              void* d_out, int out_size, void* d_ws, size_t ws_size,
                              hipStream_t stream)
{
  const float* x  = (const float*)d_in[0];
  const float* W0 = (const float*)d_in[1];
  const float* b0 = (const float*)d_in[2];
  const float* W1 = (const float*)d_in[3];
  const float* b1 = (const float*)d_in[4];
  const float* gW = (const float*)d_in[5];
  const float* ga = (const float*)d_in[6];
  const float* cW = (const float*)d_in[7];
  const float* cb = (const float*)d_in[8];
  const float* dW = (const float*)d_in[9];
  const float* db = (const float*)d_in[10];
  float* out = (float*)d_out;

  char* w = (char*)d_ws;
  auto alloc = [&](size_t bytes) { char* p = w; w += (bytes + 255) & ~(size_t)255; return p; };
  u16 *W0p[3], *W1p[3], *gWp[3], *h1p[3], *hp[3];
  for (int p = 0; p < 3; ++p) W0p[p] = (u16*)alloc((size_t)D_IN * H1_DIM * 2);
  for (int p = 0; p < 3; ++p) W1p[p] = (u16*)alloc((size_t)H1_DIM * H2_DIM * 2);
  for (int p = 0; p < 3; ++p) gWp[p] = (u16*)alloc((size_t)H2_DIM * G_DIM * 2);
  for (int p = 0; p < 3; ++p) h1p[p] = (u16*)alloc((size_t)N_PTS * H1_DIM * 2);
  for (int p = 0; p < 3; ++p) hp[p]  = (u16*)alloc((size_t)N_PTS * H2_DIM * 2);
  float* hF  = (float*)alloc((size_t)N_PTS * H2_DIM * 4);
  float* WhF = (float*)alloc((size_t)N_PTS * G_DIM * 4);
  float* sqv = (float*)alloc(N_PTS * 4);
  float* f1v = (float*)alloc(N_PTS * 4);
  float* f2v = (float*)alloc(N_PTS * 4);
  float* Wc  = (float*)alloc(64 * NOUT * 4);
  float* bc  = (float*)alloc(64 * 4);
  float* Sb  = (float*)w;

  size_t avail = (ws_size > (size_t)(w - (char*)d_ws)) ? (ws_size - (size_t)(w - (char*)d_ws)) / 4 : 0;
  int rowblk = 128;
  const int rcand[] = {768, 512, 384, 256, 128};
  for (int c : rcand) { if ((size_t)c * N_PTS <= avail) { rowblk = c; break; } }

  trans_split<<<(D_IN * H1_DIM + 255) / 256, 256, 0, stream>>>(W0, W0p[0], W0p[1], W0p[2], D_IN, H1_DIM);
  trans_split<<<(H1_DIM * H2_DIM + 255) / 256, 256, 0, stream>>>(W1, W1p[0], W1p[1], W1p[2], H1_DIM, H2_DIM);
  trans_split<<<(H2_DIM * G_DIM + 255) / 256, 256, 0, stream>>>(gW, gWp[0], gWp[1], gWp[2], H2_DIM, G_DIM);
  prep_head<<<1, 256, 0, stream>>>(cW, cb, dW, db, Wc, bc);

  // h1 = relu(x @ W0 + b0)  -> 3-plane split
  mfma_gemm<true, true, true, false, true><<<dim3(H1_DIM / 64, N_PTS / 128), 256, 0, stream>>>(
      x, nullptr, nullptr, W0p[0], W0p[1], W0p[2], b0,
      nullptr, h1p[0], h1p[1], h1p[2], D_IN, H1_DIM);
  // h = relu(h1 @ W1 + b1)  -> fp32 + 3-plane split
  mfma_gemm<false, true, true, true, true><<<dim3(H2_DIM / 64, N_PTS / 128), 256, 0, stream>>>(
      h1p[0], h1p[1], h1p[2], W1p[0], W1p[1], W1p[2], b1,
      hF, hp[0], hp[1], hp[2], H1_DIM, H2_DIM);
  // Wh = h @ gat_W  -> fp32
  mfma_gemm<false, false, false, true, false><<<dim3(G_DIM / 64, N_PTS / 128), 256, 0, stream>>>(
      hp[0], hp[1], hp[2], gWp[0], gWp[1], gWp[2], nullptr,
      WhF, nullptr, nullptr, nullptr, H2_DIM, G_DIM);

  row_stats<<<N_PTS / 256, 256, 0, stream>>>(hF, WhF, ga, sqv, f1v, f2v);

  // Row-blocked Gram panel (S = h @ h^T) + fused select/attention/head
  for (int b = 0; b < N_PTS / rowblk; ++b) {
    mfma_gemm<false, false, false, true, false><<<dim3(N_PTS / 64, rowblk / 128), 256, 0, stream>>>(
        hp[0] + (size_t)b * rowblk * H2_DIM, hp[1] + (size_t)b * rowblk * H2_DIM,
        hp[2] + (size_t)b * rowblk * H2_DIM, hp[0], hp[1], hp[2], nullptr,
        Sb, nullptr, nullptr, nullptr, H2_DIM, N_PTS);
    topk_att<<<rowblk, 256, 0, stream>>>(Sb, sqv, f1v, f2v, WhF, Wc, bc, out, b * rowblk);
  }
}

// Round 5
// 230.838 us; speedup vs baseline: 3.3571x; 1.8445x over previous
//
#include <hip/hip_runtime.h>
#include <float.h>

#define N_PTS 6144
#define D_IN  512
#define H1_DIM 256
#define H2_DIM 128
#define G_DIM  64
#define KNN    32
#define NOUT   22

typedef short s8v __attribute__((ext_vector_type(8)));   // 8 bf16 in 4 VGPR
typedef float f32x4 __attribute__((ext_vector_type(4)));
typedef unsigned short u16;

__device__ __forceinline__ u16 f2bf(float f) {
  unsigned u = __float_as_uint(f);
  u += 0x7FFFu + ((u >> 16) & 1u);          // RNE to bf16
  return (u16)(u >> 16);
}
__device__ __forceinline__ float bf2f(u16 s) {
  return __uint_as_float(((unsigned)s) << 16);
}
__device__ __forceinline__ void split3(float v, u16& a0, u16& a1, u16& a2) {
  a0 = f2bf(v);
  float r1 = v - bf2f(a0);
  a1 = f2bf(r1);
  a2 = f2bf(r1 - bf2f(a1));
}

// ---------------------------------------------------------------------------
// MFMA GEMM, 3-way bf16 split, 6-term schedule (fp32-equivalent).
// C[M,N] = A[M,K] * B^T[N,K].  BN=64, BK=32, 4 waves (2x2), wave tile (BM/2)x32.
// SPLITK: gridDim.z K-slices, raw partial write; else fused bias/relu/split.
// LDS swizzle: slot' = slot ^ ((row>>1)&3)  (32-col rows, 2-way max).
// ---------------------------------------------------------------------------
template<int BM, bool AF32, bool SPLITK, bool BIAS, bool RELU, bool WF32, bool WSPLIT>
__global__ __launch_bounds__(256, 3) void mfma_gemm(
    const void* __restrict__ A0any, const u16* __restrict__ A1_, const u16* __restrict__ A2_,
    const u16* __restrict__ B0_, const u16* __restrict__ B1_, const u16* __restrict__ B2_,
    const float* __restrict__ bias,
    float* __restrict__ Cf, u16* __restrict__ C0, u16* __restrict__ C1, u16* __restrict__ C2,
    int Ktot, int Ks, int ldC, size_t MN)
{
  const int MT = BM / 32, NT = 2;
  __shared__ u16 lds[(BM + 64) * 32 * 3];
  u16* Ap[3] = { lds, lds + BM * 32, lds + 2 * BM * 32 };
  u16* Bp[3] = { lds + 3 * BM * 32, lds + 3 * BM * 32 + 2048, lds + 3 * BM * 32 + 4096 };

  const int t = threadIdx.x;
  const int lane = t & 63, wave = t >> 6;
  const int wm = wave >> 1, wn = wave & 1;
  const int m0 = blockIdx.y * BM, n0 = blockIdx.x * 64;
  const int kz = blockIdx.z * Ks;

  f32x4 acc[MT][NT] = {};

  for (int k0 = 0; k0 < Ks; k0 += 32) {
    if (k0) __syncthreads();
    const int kb = kz + k0;
    // ---- stage A (BM x 32 x 3 planes) ----
    if (AF32) {
      const float* A = (const float*)A0any;
      #pragma unroll
      for (int c0 = 0; c0 < BM * 4; c0 += 256) {
        int c = c0 + t;
        int row = c >> 2, slot = c & 3;
        const float* g = A + (size_t)(m0 + row) * Ktot + kb + slot * 8;
        f32x4 fa = *(const f32x4*)g;
        f32x4 fb = *(const f32x4*)(g + 4);
        int dst = row * 32 + ((slot ^ ((row >> 1) & 3)) << 3);
        s8v v0, v1, v2;
        #pragma unroll
        for (int e = 0; e < 4; ++e) {
          u16 a0, a1, a2; split3(fa[e], a0, a1, a2);
          v0[e] = (short)a0; v1[e] = (short)a1; v2[e] = (short)a2;
        }
        #pragma unroll
        for (int e = 0; e < 4; ++e) {
          u16 a0, a1, a2; split3(fb[e], a0, a1, a2);
          v0[4 + e] = (short)a0; v1[4 + e] = (short)a1; v2[4 + e] = (short)a2;
        }
        *(s8v*)(Ap[0] + dst) = v0;
        *(s8v*)(Ap[1] + dst) = v1;
        *(s8v*)(Ap[2] + dst) = v2;
      }
    } else {
      const u16* As[3] = { (const u16*)A0any, A1_, A2_ };
      #pragma unroll
      for (int c0 = 0; c0 < BM * 4; c0 += 256) {
        int c = c0 + t;
        int row = c >> 2, slot = c & 3;
        size_t g = (size_t)(m0 + row) * Ktot + kb + slot * 8;
        int dst = row * 32 + ((slot ^ ((row >> 1) & 3)) << 3);
        #pragma unroll
        for (int p = 0; p < 3; ++p)
          *(s8v*)(Ap[p] + dst) = *(const s8v*)(As[p] + g);
      }
    }
    // ---- stage B (64 x 32 x 3 planes), exactly one chunk/thread ----
    {
      const u16* Bs[3] = { B0_, B1_, B2_ };
      int row = t >> 2, slot = t & 3;
      size_t g = (size_t)(n0 + row) * Ktot + kb + slot * 8;
      int dst = row * 32 + ((slot ^ ((row >> 1) & 3)) << 3);
      #pragma unroll
      for (int p = 0; p < 3; ++p)
        *(s8v*)(Bp[p] + dst) = *(const s8v*)(Bs[p] + g);
    }
    __syncthreads();

    // ---- fragments + MFMA ----
    s8v af[3][MT], bf[3][NT];
    #pragma unroll
    for (int mt = 0; mt < MT; ++mt) {
      int r = wm * (BM / 2) + mt * 16 + (lane & 15);
      int off = r * 32 + (((lane >> 4) ^ ((r >> 1) & 3)) << 3);
      #pragma unroll
      for (int p = 0; p < 3; ++p) af[p][mt] = *(const s8v*)(Ap[p] + off);
    }
    #pragma unroll
    for (int nt = 0; nt < NT; ++nt) {
      int r = wn * 32 + nt * 16 + (lane & 15);
      int off = r * 32 + (((lane >> 4) ^ ((r >> 1) & 3)) << 3);
      #pragma unroll
      for (int p = 0; p < 3; ++p) bf[p][nt] = *(const s8v*)(Bp[p] + off);
    }
    #pragma unroll
    for (int mt = 0; mt < MT; ++mt)
      #pragma unroll
      for (int nt = 0; nt < NT; ++nt) {
        f32x4 a = acc[mt][nt];
        a = __builtin_amdgcn_mfma_f32_16x16x32_bf16(af[0][mt], bf[0][nt], a, 0, 0, 0);
        a = __builtin_amdgcn_mfma_f32_16x16x32_bf16(af[0][mt], bf[1][nt], a, 0, 0, 0);
        a = __builtin_amdgcn_mfma_f32_16x16x32_bf16(af[1][mt], bf[0][nt], a, 0, 0, 0);
        a = __builtin_amdgcn_mfma_f32_16x16x32_bf16(af[1][mt], bf[1][nt], a, 0, 0, 0);
        a = __builtin_amdgcn_mfma_f32_16x16x32_bf16(af[0][mt], bf[2][nt], a, 0, 0, 0);
        a = __builtin_amdgcn_mfma_f32_16x16x32_bf16(af[2][mt], bf[0][nt], a, 0, 0, 0);
        acc[mt][nt] = a;
      }
  }

  // ---- epilogue: C/D layout col=lane&15, row=(lane>>4)*4+v ----
  #pragma unroll
  for (int mt = 0; mt < MT; ++mt) {
    #pragma unroll
    for (int nt = 0; nt < NT; ++nt) {
      int col = n0 + wn * 32 + nt * 16 + (lane & 15);
      float bv = (BIAS && !SPLITK) ? bias[col] : 0.f;
      #pragma unroll
      for (int v = 0; v < 4; ++v) {
        int row = m0 + wm * (BM / 2) + mt * 16 + (lane >> 4) * 4 + v;
        float val = acc[mt][nt][v] + bv;
        size_t o = (size_t)row * ldC + col;
        if (SPLITK) {
          Cf[(size_t)blockIdx.z * MN + o] = val;
        } else {
          if (RELU) val = fmaxf(val, 0.f);
          if (WF32) Cf[o] = val;
          if (WSPLIT) {
            u16 a0, a1, a2; split3(val, a0, a1, a2);
            C0[o] = a0; C1[o] = a1; C2[o] = a2;
          }
        }
      }
    }
  }
}

// Sum S split-K partials, apply bias/relu, write fp32 and/or 3-plane split.
template<int S, bool BIAS, bool RELU, bool WF32, bool WSPLIT>
__global__ void combine(const float* __restrict__ P, const float* __restrict__ bias,
                        size_t MN, int Ncols,
                        float* __restrict__ Cf, u16* __restrict__ C0,
                        u16* __restrict__ C1, u16* __restrict__ C2)
{
  size_t idx = ((size_t)blockIdx.x * 256 + threadIdx.x) * 4;
  if (idx >= MN) return;
  f32x4 s = *(const f32x4*)(P + idx);
  #pragma unroll
  for (int z = 1; z < S; ++z) s += *(const f32x4*)(P + (size_t)z * MN + idx);
  int n = (int)(idx % (size_t)Ncols);
  #pragma unroll
  for (int e = 0; e < 4; ++e) {
    float v = s[e] + (BIAS ? bias[n + e] : 0.f);
    if (RELU) v = fmaxf(v, 0.f);
    if (WF32) Cf[idx + e] = v;
    if (WSPLIT) {
      u16 a0, a1, a2; split3(v, a0, a1, a2);
      C0[idx + e] = a0; C1[idx + e] = a1; C2[idx + e] = a2;
    }
  }
}

// W [K,N] fp32 -> W^T 3-plane bf16 split [N,K]
__global__ void trans_split(const float* __restrict__ W, u16* __restrict__ p0,
                            u16* __restrict__ p1, u16* __restrict__ p2, int K, int N)
{
  int id = blockIdx.x * 256 + threadIdx.x;
  if (id >= K * N) return;
  int k = id / N, n = id % N;
  u16 a0, a1, a2;
  split3(W[id], a0, a1, a2);
  size_t o = (size_t)n * K + k;
  p0[o] = a0; p1[o] = a1; p2[o] = a2;
}

// Collapse tiled heads: Wc[64][22], bc[22]
__global__ void prep_head(const float* __restrict__ cW, const float* __restrict__ cb,
                          const float* __restrict__ dW, const float* __restrict__ db,
                          float* __restrict__ Wc, float* __restrict__ bc)
{
  int t = threadIdx.x;
  for (int idx = t; idx < 64 * NOUT; idx += 256) {
    int g = idx / NOUT, c = idx % NOUT;
    float s = 0.f;
    if (c < 16) {
      for (int r = 0; r < 8; ++r) s += cW[(r * 64 + g) * 16 + c];
    } else {
      int k = (c - 16) >> 1, o = (c - 16) & 1;
      for (int r = 0; r < 8; ++r) s += dW[k * 1024 + (r * 64 + g) * 2 + o];
    }
    Wc[idx] = s;
  }
  if (t < NOUT) bc[t] = (t < 16) ? cb[t] : db[t - 16];
}

__global__ void row_stats(const float* __restrict__ h, const float* __restrict__ Wh,
                          const float* __restrict__ ga, float* __restrict__ sq,
                          float* __restrict__ f1, float* __restrict__ f2)
{
  int i = blockIdx.x * 256 + threadIdx.x;
  const float* hr = h + (size_t)i * H2_DIM;
  float s = 0.f;
  for (int k = 0; k < H2_DIM; ++k) { float v = hr[k]; s = fmaf(v, v, s); }
  sq[i] = s;
  const float* wr = Wh + (size_t)i * G_DIM;
  float a = 0.f, b = 0.f;
  for (int g = 0; g < G_DIM; ++g) {
    float w = wr[g];
    a = fmaf(w, ga[g], a);
    b = fmaf(w, ga[G_DIM + g], b);
  }
  f1[i] = a; f2[i] = b;
}

// ---------------------------------------------------------------------------
// Per-row: radix-select 32 smallest keys (sq_j - 2*S_ij, j!=i), then fused
// masked softmax + sparse att@Wh + elu + 64->22 head.
// ---------------------------------------------------------------------------
__global__ __launch_bounds__(256) void topk_att(const float* __restrict__ Sb,
    const float* __restrict__ sq, const float* __restrict__ f1, const float* __restrict__ f2,
    const float* __restrict__ Wh, const float* __restrict__ Wc, const float* __restrict__ bc,
    float* __restrict__ out, int m0)
{
  const int t = threadIdx.x;
  const int lane = t & 63, wv = t >> 6;
  const int i = m0 + blockIdx.x;
  const float* Srow = Sb + (size_t)blockIdx.x * N_PTS;

  __shared__ int hist[256];
  __shared__ int wtot[4];
  __shared__ int sD0, sB0, sD1, sB1;
  __shared__ int wcnt, ccnt, ovf;
  __shared__ unsigned cand[64];
  __shared__ unsigned long long redr[4];
  __shared__ int neigh[33];
  __shared__ float attL[33];
  __shared__ float hp4[4][64];
  __shared__ float hpf[64];
  __shared__ float WcL[64 * NOUT];

  for (int idx = t; idx < 64 * NOUT; idx += 256) WcL[idx] = Wc[idx];

  unsigned u[24];
  #pragma unroll
  for (int m = 0; m < 24; ++m) {
    int j = t + (m << 8);
    float f = fmaf(-2.f, Srow[j], sq[j]);
    unsigned ub = __float_as_uint(f);
    unsigned uu = (ub & 0x80000000u) ? ~ub : (ub | 0x80000000u);
    u[m] = (j == i) ? 0xFFFFFFFFu : uu;
  }

  hist[t] = 0;
  if (t == 0) { wcnt = 0; ccnt = 0; ovf = 0; }
  __syncthreads();
  #pragma unroll
  for (int m = 0; m < 24; ++m) atomicAdd(&hist[u[m] >> 24], 1);
  __syncthreads();
  {
    int v = hist[t], x = v;
    #pragma unroll
    for (int d = 1; d < 64; d <<= 1) { int o = __shfl_up(x, (unsigned)d); if (lane >= d) x += o; }
    if (lane == 63) wtot[wv] = x;
    __syncthreads();
    int off = 0;
    for (int w = 0; w < wv; ++w) off += wtot[w];
    int incl = x + off, excl = incl - v;
    if (excl < 32 && 32 <= incl) { sD0 = t; sB0 = excl; }
  }
  __syncthreads();
  const int D0 = sD0;
  const int need2 = 32 - sB0;
  hist[t] = 0;
  __syncthreads();
  #pragma unroll
  for (int m = 0; m < 24; ++m)
    if ((int)(u[m] >> 24) == D0) atomicAdd(&hist[(u[m] >> 16) & 255], 1);
  __syncthreads();
  {
    int v = hist[t], x = v;
    #pragma unroll
    for (int d = 1; d < 64; d <<= 1) { int o = __shfl_up(x, (unsigned)d); if (lane >= d) x += o; }
    if (lane == 63) wtot[wv] = x;
    __syncthreads();
    int off = 0;
    for (int w = 0; w < wv; ++w) off += wtot[w];
    int incl = x + off, excl = incl - v;
    if (excl < need2 && need2 <= incl) { sD1 = t; sB1 = excl; }
  }
  __syncthreads();
  const unsigned P16 = ((unsigned)D0 << 8) | (unsigned)sD1;
  const int rem2 = need2 - sB1;

  #pragma unroll
  for (int m = 0; m < 24; ++m) {
    unsigned p = u[m] >> 16;
    int j = t + (m << 8);
    if (p < P16) {
      int w = atomicAdd(&wcnt, 1);
      neigh[w] = j;
    } else if (p == P16) {
      int c = atomicAdd(&ccnt, 1);
      if (c < 64) cand[c] = ((u[m] & 0xFFFFu) << 13) | (unsigned)j;
      else ovf = 1;
    }
  }
  __syncthreads();

  if (!ovf) {
    if (t < 64) {
      unsigned v = (lane < ccnt) ? cand[lane] : 0xFFFFFFFFu;
      for (int k = 2; k <= 64; k <<= 1)
        for (int j2 = k >> 1; j2 >= 1; j2 >>= 1) {
          unsigned o = __shfl_xor(v, j2);
          bool keepMin = ((lane & j2) == 0) == ((lane & k) == 0);
          v = keepMin ? (v < o ? v : o) : (v > o ? v : o);
        }
      if (lane < rem2) neigh[wcnt + lane] = (int)(v & 0x1FFFu);
      if (lane == 0) neigh[32] = i;
    }
  } else {
    unsigned long long lv = ~0ull; int lm = 0;
    #pragma unroll
    for (int m = 0; m < 24; ++m) {
      unsigned long long rk = ((unsigned long long)u[m] << 13) | (unsigned)(t + (m << 8));
      if (rk < lv) { lv = rk; lm = m; }
    }
    for (int it = 0; it < KNN; ++it) {
      unsigned long long v = lv;
      for (int off2 = 32; off2 > 0; off2 >>= 1) {
        unsigned long long o = __shfl_xor(v, off2);
        if (o < v) v = o;
      }
      if (lane == 0) redr[wv] = v;
      __syncthreads();
      v = redr[0];
      for (int w = 1; w < 4; ++w) v = (redr[w] < v) ? redr[w] : v;
      if (t == 0) neigh[it] = (int)(v & 0x1FFFu);
      if (v == lv) {
        #pragma unroll
        for (int m = 0; m < 24; ++m) if (m == lm) u[m] = 0xFFFFFFFFu;
        lv = ~0ull; lm = 0;
        #pragma unroll
        for (int m = 0; m < 24; ++m) {
          unsigned long long rk = ((unsigned long long)u[m] << 13) | (unsigned)(t + (m << 8));
          if (rk < lv) { lv = rk; lm = m; }
        }
      }
      __syncthreads();
    }
    if (t == 0) neigh[32] = i;
  }
  __syncthreads();

  if (t < 64) {
    float e = -FLT_MAX;
    if (t < 33) {
      float raw = f1[i] + f2[neigh[t]];
      e = raw > 0.f ? raw : 0.2f * raw;
    }
    float mx = e;
    #pragma unroll
    for (int off = 32; off > 0; off >>= 1) mx = fmaxf(mx, __shfl_xor(mx, off));
    float ex = (t < 33) ? expf(e - mx) : 0.f;
    float sm = ex;
    #pragma unroll
    for (int off = 32; off > 0; off >>= 1) sm += __shfl_xor(sm, off);
    if (t < 33) attL[t] = ex / sm;
  }
  __syncthreads();

  {
    int g = t & 63, q = t >> 6;
    float s = 0.f;
    for (int m = q; m < 33; m += 4)
      s = fmaf(attL[m], Wh[(size_t)neigh[m] * G_DIM + g], s);
    hp4[q][g] = s;
  }
  __syncthreads();
  if (t < 64) {
    float v = hp4[0][t] + hp4[1][t] + hp4[2][t] + hp4[3][t];
    hpf[t] = v > 0.f ? v : expm1f(v);
  }
  __syncthreads();
  if (t < NOUT) {
    float o = bc[t];
    for (int g = 0; g < 64; ++g) o = fmaf(hpf[g], WcL[g * NOUT + t], o);
    out[(size_t)i * NOUT + t] = o;
  }
}

extern "C" void kernel_launch(void* const* d_in, const int* in_sizes, int n_in,
                              void* d_out, int out_size, void* d_ws, size_t ws_size,
                              hipStream_t stream)
{
  const float* x  = (const float*)d_in[0];
  const float* W0 = (const float*)d_in[1];
  const float* b0 = (const float*)d_in[2];
  const float* W1 = (const float*)d_in[3];
  const float* b1 = (const float*)d_in[4];
  const float* gW = (const float*)d_in[5];
  const float* ga = (const float*)d_in[6];
  const float* cW = (const float*)d_in[7];
  const float* cb = (const float*)d_in[8];
  const float* dW = (const float*)d_in[9];
  const float* db = (const float*)d_in[10];
  float* out = (float*)d_out;

  char* base = (char*)d_ws;
  char* w = base;
  auto alloc = [&](size_t bytes) { char* p = w; w += (bytes + 255) & ~(size_t)255; return p; };
  u16 *W0p[3], *W1p[3], *gWp[3], *h1p[3], *hp[3];
  for (int p = 0; p < 3; ++p) W0p[p] = (u16*)alloc((size_t)D_IN * H1_DIM * 2);
  for (int p = 0; p < 3; ++p) W1p[p] = (u16*)alloc((size_t)H1_DIM * H2_DIM * 2);
  for (int p = 0; p < 3; ++p) gWp[p] = (u16*)alloc((size_t)H2_DIM * G_DIM * 2);
  for (int p = 0; p < 3; ++p) h1p[p] = (u16*)alloc((size_t)N_PTS * H1_DIM * 2);
  for (int p = 0; p < 3; ++p) hp[p]  = (u16*)alloc((size_t)N_PTS * H2_DIM * 2);
  float* hF  = (float*)alloc((size_t)N_PTS * H2_DIM * 4);
  float* WhF = (float*)alloc((size_t)N_PTS * G_DIM * 4);
  float* sqv = (float*)alloc(N_PTS * 4);
  float* f1v = (float*)alloc(N_PTS * 4);
  float* f2v = (float*)alloc(N_PTS * 4);
  float* Wc  = (float*)alloc(64 * NOUT * 4);
  float* bc  = (float*)alloc(64 * 4);

  // split-K partials (transient; Sb aliases this region afterwards)
  char* pbase = w;
  const size_t MN1 = (size_t)N_PTS * H1_DIM;
  const size_t MN2 = (size_t)N_PTS * H2_DIM;
  const size_t MN3 = (size_t)N_PTS * G_DIM;
  float* P1 = (float*)alloc(4 * MN1 * 4);
  float* P2 = (float*)alloc(4 * MN2 * 4);
  float* P3 = (float*)alloc(4 * MN3 * 4);
  float* Sb = (float*)pbase;

  size_t used_persist = (size_t)(pbase - base);
  size_t avail = (ws_size > used_persist) ? (ws_size - used_persist) / 4 : 0;
  int rowblk = 128;
  const int rcand[] = {6144, 3072, 1536, 768, 384, 256, 128};
  for (int c : rcand) { if ((size_t)c * N_PTS <= avail) { rowblk = c; break; } }

  trans_split<<<(D_IN * H1_DIM + 255) / 256, 256, 0, stream>>>(W0, W0p[0], W0p[1], W0p[2], D_IN, H1_DIM);
  trans_split<<<(H1_DIM * H2_DIM + 255) / 256, 256, 0, stream>>>(W1, W1p[0], W1p[1], W1p[2], H1_DIM, H2_DIM);
  trans_split<<<(H2_DIM * G_DIM + 255) / 256, 256, 0, stream>>>(gW, gWp[0], gWp[1], gWp[2], H2_DIM, G_DIM);
  prep_head<<<1, 256, 0, stream>>>(cW, cb, dW, db, Wc, bc);

  // h1 = relu(x @ W0 + b0): split-K=4 (Ks=128) then combine -> planes
  mfma_gemm<64, true, true, false, false, false, false>
      <<<dim3(H1_DIM / 64, N_PTS / 64, 4), 256, 0, stream>>>(
      x, nullptr, nullptr, W0p[0], W0p[1], W0p[2], nullptr,
      P1, nullptr, nullptr, nullptr, D_IN, D_IN / 4, H1_DIM, MN1);
  combine<4, true, true, false, true><<<(int)(MN1 / 1024), 256, 0, stream>>>(
      P1, b0, MN1, H1_DIM, nullptr, h1p[0], h1p[1], h1p[2]);

  // h = relu(h1 @ W1 + b1): split-K=4 (Ks=64) -> fp32 + planes
  mfma_gemm<64, false, true, false, false, false, false>
      <<<dim3(H2_DIM / 64, N_PTS / 64, 4), 256, 0, stream>>>(
      h1p[0], h1p[1], h1p[2], W1p[0], W1p[1], W1p[2], nullptr,
      P2, nullptr, nullptr, nullptr, H1_DIM, H1_DIM / 4, H2_DIM, MN2);
  combine<4, true, true, true, true><<<(int)(MN2 / 1024), 256, 0, stream>>>(
      P2, b1, MN2, H2_DIM, hF, hp[0], hp[1], hp[2]);

  // Wh = h @ gat_W: split-K=4 (Ks=32) -> fp32
  mfma_gemm<64, false, true, false, false, false, false>
      <<<dim3(G_DIM / 64, N_PTS / 64, 4), 256, 0, stream>>>(
      hp[0], hp[1], hp[2], gWp[0], gWp[1], gWp[2], nullptr,
      P3, nullptr, nullptr, nullptr, H2_DIM, H2_DIM / 4, G_DIM, MN3);
  combine<4, false, false, true, false><<<(int)(MN3 / 1024), 256, 0, stream>>>(
      P3, nullptr, MN3, G_DIM, WhF, nullptr, nullptr, nullptr);

  row_stats<<<N_PTS / 256, 256, 0, stream>>>(hF, WhF, ga, sqv, f1v, f2v);

  // Gram panel(s): S = h @ h^T (BM=128 tile), then fused select/attention/head
  for (int b = 0; b < N_PTS / rowblk; ++b) {
    mfma_gemm<128, false, false, false, false, true, false>
        <<<dim3(N_PTS / 64, rowblk / 128, 1), 256, 0, stream>>>(
        hp[0] + (size_t)b * rowblk * H2_DIM, hp[1] + (size_t)b * rowblk * H2_DIM,
        hp[2] + (size_t)b * rowblk * H2_DIM, hp[0], hp[1], hp[2], nullptr,
        Sb, nullptr, nullptr, nullptr, H2_DIM, H2_DIM, N_PTS, 0);
    topk_att<<<rowblk, 256, 0, stream>>>(Sb, sqv, f1v, f2v, WhF, Wc, bc, out, b * rowblk);
  }
}